// Round 9
// baseline (584.127 us; speedup 1.0000x reference)
//
#include <hip/hip_runtime.h>
#include <hip/hip_bf16.h>
#include <math.h>

#define NN    50000
#define EE    400000
#define NINP  256
#define HH    4
#define DD    32
#define HIDD  128
#define TNN   4
#define TEE   6
#define LLL   2
#define NOUTT 16
#define TILES 786                 // NN/64 + TNN + 1
#define NROWS 50304               // TILES*64, >= meta[4]
#define NB2   197                 // (NROWS+255)/256 scan blocks

// RULE: every LDS array row stride must be a multiple of 4 fp32 / 8 bf16
// elements so vector b128 accesses stay 16B-aligned (2 crashed rounds).
// RULE: every LDS staging loop must cover rows*cols/threads slots (round 6).
// RULE (round 10): don't feed MFMA straight from global — L2 latency stalls the
// pipe. (round 11): hold the k-invariant operand (A) in REGISTERS, B in LDS.
// RULE (round 12): Wf and WlaT are stored XOR-SWIZZLED (ushort col ^= (row&7)<<3
// per 128-col half-row) + panel-linear for linear global_load_lds staging.
// RULE (round 14): raw s_barrier + counted-vmcnt pipelining hung the GPU — do
// not reattempt. RULE (round 15): one-phase-per-block with SCATTERED A-gather
// regressed 45% — but with DENSE row-space A (round 16+) finer SPLIT is safe
// (round 21: SPLIT 2->4, A-prologue is 16 dense 4KB-block loads, L2-hot).
// RULE (round 16): permuted row space (h/hb/aggb/kqvb by tile row, kqvb
// plane-major [13][NROWS][128]) made GEMM traffic dense — the win.
// RULE (round 19): NEVER use a reference-capturing lambda for register selects
// — AMDGPUPromoteAlloca turned the capture struct into 48KB of per-WG LDS with
// runtime indexing (2M bank conflicts, occupancy 63->24%, k_edge 66->134us).
// Use pure nested-ternary EXPRESSIONS over named registers instead.
// RULE (round 20): k_edge is gather-LINE-bound: vhat was 4x64B chunks in 4
// planes (50% line util). V-section columns are (t*4+h)*32+d so vhat[row,t] =
// plane 7+t, cols h*32+d — one dense 256B read per edge (FETCH 184->134MB).

typedef __attribute__((ext_vector_type(8))) short bf16x8;
typedef __attribute__((ext_vector_type(4))) float f32x4;

__device__ __forceinline__ float bf_lo(unsigned u) { return __uint_as_float(u << 16); }
__device__ __forceinline__ float bf_hi(unsigned u) { return __uint_as_float(u & 0xFFFF0000u); }
__device__ __forceinline__ unsigned f2bf(float f) {
    unsigned u = __float_as_uint(f);
    u += 0x7FFFu + ((u >> 16) & 1u);
    return (u >> 16);
}

// async global->LDS DMA, 16B per lane. LDS dest = wave-uniform base + lane*16.
__device__ __forceinline__ void gload_lds16(const unsigned short* g, unsigned short* l) {
    __builtin_amdgcn_global_load_lds(
        (__attribute__((address_space(1))) void*)(g),
        (__attribute__((address_space(3))) void*)(l), 16, 0, 0);
}

// ---------------- workspace init ----------------
__global__ void k_init(int* __restrict__ deg, int* __restrict__ cur, int* __restrict__ ncnt,
                       int* __restrict__ ncur, int* __restrict__ nperm) {
    int i = blockIdx.x * 256 + threadIdx.x;
    if (i < NROWS) { deg[i] = 0; cur[i] = 0; nperm[i] = -1; }
    if (i < 16) { ncnt[i] = 0; ncur[i] = 0; }
}

// ---------------- node typing / permutation ----------------
__global__ void k_count_types(const int* __restrict__ ntype, int* __restrict__ ncnt) {
    int n = blockIdx.x * 256 + threadIdx.x;
    int lane = threadIdx.x & 63;
    int t = (n < NN) ? ntype[n] : -1;
#pragma unroll
    for (int tt = 0; tt < TNN; tt++) {
        unsigned long long mask = __ballot(t == tt);
        if (mask && lane == (__ffsll((unsigned long long)mask) - 1))
            atomicAdd(&ncnt[tt], __popcll(mask));
    }
}
__global__ void k_meta(const int* __restrict__ ncnt, int* __restrict__ meta) {
    if (threadIdx.x == 0) {
        int acc = 0;
        meta[0] = 0;
        for (int t = 0; t < TNN; t++) { acc += ((ncnt[t] + 63) >> 6) << 6; meta[t + 1] = acc; }
    }
}
__global__ void k_scatter_nodes(const int* __restrict__ ntype, const int* __restrict__ meta,
                                int* __restrict__ ncur, int* __restrict__ nperm,
                                int* __restrict__ iperm) {
    int n = blockIdx.x * 256 + threadIdx.x;
    int lane = threadIdx.x & 63;
    int t = (n < NN) ? ntype[n] : -1;
#pragma unroll
    for (int tt = 0; tt < TNN; tt++) {
        unsigned long long mask = __ballot(t == tt);
        if (t == tt) {
            int rank = __popcll(mask & ((1ull << lane) - 1ull));
            int leader = __ffsll((unsigned long long)mask) - 1;
            int b = 0;
            if (rank == 0) b = atomicAdd(&ncur[tt], __popcll(mask));
            b = __shfl(b, leader);
            int slot = meta[tt] + b + rank;
            nperm[slot] = n;
            iperm[n] = slot;
        }
    }
}

// ---------------- CSR over PERMUTED rows ----------------
__global__ void k_count_edges(const int* __restrict__ dst, const int* __restrict__ iperm,
                              int* __restrict__ deg) {
    int e = blockIdx.x * 256 + threadIdx.x;
    if (e < EE) atomicAdd(&deg[iperm[dst[e]]], 1);
}
// 3-pass scan over NROWS
__global__ void k_scan1(const int* __restrict__ deg, int* __restrict__ bsum) {
    int i = blockIdx.x * 256 + threadIdx.x;
    int lane = threadIdx.x & 63, wv = threadIdx.x >> 6;
    __shared__ int ws[4];
    int x = (i < NROWS) ? deg[i] : 0;
#pragma unroll
    for (int off = 1; off < 64; off <<= 1) x += __shfl_xor(x, off);
    if (lane == 0) ws[wv] = x;
    __syncthreads();
    if (threadIdx.x == 0) bsum[blockIdx.x] = ws[0] + ws[1] + ws[2] + ws[3];
}
__global__ void k_scan2(const int* __restrict__ bsum, int* __restrict__ bpre) {
    __shared__ int ws[4];
    int tid = threadIdx.x, lane = tid & 63, wv = tid >> 6;
    int v = (tid < NB2) ? bsum[tid] : 0;
    int x = v;
#pragma unroll
    for (int off = 1; off < 64; off <<= 1) {
        int y = __shfl_up(x, off);
        if (lane >= off) x += y;
    }
    if (lane == 63) ws[wv] = x;
    __syncthreads();
    if (tid == 0) { int a = 0; for (int w = 0; w < 4; w++) { int s = ws[w]; ws[w] = a; a += s; } }
    __syncthreads();
    if (tid < NB2) bpre[tid] = x - v + ws[wv];
}
__global__ void k_scan3(const int* __restrict__ deg, const int* __restrict__ bpre,
                        int* __restrict__ offs) {
    int b = blockIdx.x;
    int tid = threadIdx.x, lane = tid & 63, wv = tid >> 6;
    int i = b * 256 + tid;
    __shared__ int ws[4];
    int v = (i < NROWS) ? deg[i] : 0;
    int x = v;
#pragma unroll
    for (int off = 1; off < 64; off <<= 1) {
        int y = __shfl_up(x, off);
        if (lane >= off) x += y;
    }
    if (lane == 63) ws[wv] = x;
    __syncthreads();
    if (tid == 0) { int a = 0; for (int w = 0; w < 4; w++) { int s = ws[w]; ws[w] = a; a += s; } }
    __syncthreads();
    if (i < NROWS) offs[i + 1] = x + ws[wv] + bpre[b];
    if (b == 0 && tid == 0) offs[0] = 0;
}
// writes packed (permuted_src<<3)|etype per CSR slot
__global__ void k_scatter_edges(const int* __restrict__ dst, const int* __restrict__ src,
                                const int* __restrict__ etype, const int* __restrict__ iperm,
                                const int* __restrict__ offs, int* __restrict__ cur,
                                unsigned* __restrict__ se) {
    int e = blockIdx.x * 256 + threadIdx.x;
    if (e < EE) {
        int d = iperm[dst[e]];
        int p = atomicAdd(&cur[d], 1);
        se[offs[d] + p] = ((unsigned)iperm[src[e]] << 3) | (unsigned)etype[e];
    }
}

// ---------------- weight transpose+convert: W[t][k][n] f32 -> WT[t][n][k] bf16 ----------
// adaptT: unswizzled (legacy k_gemm). Wf rows 0..127 and WlaT: XOR-swizzled
// (ushort col ^= (row&7)<<3) so DMA-staging GEMMs can read linearly.
__global__ void k_wt(const float* __restrict__ adapt_W, const float* __restrict__ Wk,
                     const float* __restrict__ Wla, unsigned short* __restrict__ adaptT,
                     unsigned short* __restrict__ Wf, unsigned short* __restrict__ WlaT) {
    __shared__ float Ts[64][68];  // 272B row stride
    int b = blockIdx.x, tid = threadIdx.x;
    const float* src;
    unsigned short* dst;
    int K, kt, nt, swz;
    if (b < 32) {
        int t = b >> 3, tile = b & 7;
        K = 256; kt = tile >> 1; nt = tile & 1; swz = 0;
        src = adapt_W + (size_t)t * 256 * 128;
        dst = adaptT + (size_t)t * 128 * 256;
    } else if (b < 64) {
        int b2 = b - 32, l = b2 >> 4, r = b2 & 15, t = r >> 2, tile = r & 3;
        K = 128; kt = tile >> 1; nt = tile & 1; swz = 1;
        src = Wk + (size_t)(l * 4 + t) * 16384;
        dst = Wf + (size_t)(l * TNN + t) * 1664 * 128;  // fused rows 0..127
    } else {
        int b2 = b - 64, l = b2 >> 4, r = b2 & 15, t = r >> 2, tile = r & 3;
        K = 128; kt = tile >> 1; nt = tile & 1; swz = 1;
        src = Wla + (size_t)(l * 4 + t) * 16384;
        dst = WlaT + (size_t)(l * 4 + t) * 16384;
    }
    int k0 = kt * 64, n0 = nt * 64;
#pragma unroll
    for (int it = 0; it < 4; it++) {  // 64x16 slots
        int idx = tid + it * 256;
        int row = idx >> 4, c4 = (idx & 15) * 4;
        *(float4*)(&Ts[row][c4]) = *(const float4*)(src + (size_t)(k0 + row) * 128 + n0 + c4);
    }
    __syncthreads();
#pragma unroll
    for (int it = 0; it < 2; it++) {  // 64x8 slots
        int idx = tid + it * 256;
        int nn = idx >> 3, sg = (idx & 7) * 8;
        uint4 pk;
        pk.x = f2bf(Ts[sg + 0][nn]) | (f2bf(Ts[sg + 1][nn]) << 16);
        pk.y = f2bf(Ts[sg + 2][nn]) | (f2bf(Ts[sg + 3][nn]) << 16);
        pk.z = f2bf(Ts[sg + 4][nn]) | (f2bf(Ts[sg + 5][nn]) << 16);
        pk.w = f2bf(Ts[sg + 6][nn]) | (f2bf(Ts[sg + 7][nn]) << 16);
        int col = k0 + sg;
        if (swz) col ^= (nn & 7) << 3;   // row = n0+nn, n0 % 8 == 0
        *(uint4*)(dst + (size_t)(n0 + nn) * K + col) = pk;
    }
}

// ---------------- combined weights into fused buffer (swizzled out) ----------------
// qhat columns: 128 + (h*6+t)*32 + o. vhat columns: 896 + (t*4+h)*32 + o
// (per-type contiguous so k_edge reads one dense 256B line per edge).
__global__ void k_comb(const float* __restrict__ Wq, const float* __restrict__ Wa,
                       const float* __restrict__ Wv, const float* __restrict__ Wm,
                       const float* __restrict__ pri, unsigned short* __restrict__ Wf) {
    __shared__ float Ls[128][36];
    __shared__ float Ss[32][36];
    __shared__ unsigned short Ot[32][136];
    int b = blockIdx.x, tid = threadIdx.x;
    int mode = b / 192;
    int rem = b % 192;
    int l = rem / 96;
    int rem2 = rem % 96;
    int t = rem2 / 24;
    int ht = rem2 % 24;
    int hh = ht / 6, te = ht % 6;
    const float* L = (mode == 0 ? Wq : Wv) + ((size_t)(l * TNN + t)) * 16384;
    const float* S = (mode == 0 ? Wa : Wm) + ((size_t)((l * HH + hh) * TEE + te)) * 1024;
    float ps = (mode == 0) ? pri[(l * HH + hh) * TEE + te] * 0.17677669529663687f : 1.0f;
#pragma unroll
    for (int it = 0; it < 4; it++) {  // 128x8 slots = 1024
        int idx = tid + it * 256;
        int kk = idx >> 3, c4 = (idx & 7) * 4;
        *(float4*)(&Ls[kk][c4]) = *(const float4*)(L + (size_t)kk * 128 + hh * 32 + c4);
    }
    {
        int r = tid >> 3, c4 = (tid & 7) * 4;
        *(float4*)(&Ss[r][c4]) = *(const float4*)(S + r * 32 + c4);
    }
    __syncthreads();
    int k = tid >> 1, half = tid & 1;
#pragma unroll
    for (int jj = 0; jj < 16; jj++) {
        int j = half * 16 + jj;
        float s = 0.f;
        if (mode == 0) {
#pragma unroll
            for (int o = 0; o < 32; o++) s += Ls[k][o] * Ss[j][o];
        } else {
#pragma unroll
            for (int d = 0; d < 32; d++) s += Ls[k][d] * Ss[d][j];
        }
        Ot[j][k] = (unsigned short)f2bf(s * ps);
    }
    __syncthreads();
    unsigned short* dst = Wf + ((size_t)(l * TNN + t) * 1664 + (mode == 0 ? 128 : 896)) * 128;
#pragma unroll
    for (int it = 0; it < 2; it++) {  // 32x16 slots
        int idx = tid + it * 256;
        int j = idx >> 4, sg = (idx & 15) * 8;
        uint4 pk = *(const uint4*)(&Ot[j][sg]);
        int jg = (mode == 0) ? (hh * 6 + te) * 32 + j : (te * 4 + hh) * 32 + j;
        *(uint4*)(dst + (size_t)jg * 128 + (sg ^ ((jg & 7) << 3))) = pk;
    }
}

// ---------------- adapt GEMM (K=256, fp32 A gathered by nperm; row-space out) ----
template <int K, int NCB>
__launch_bounds__(256) __global__
void k_gemm(const float* __restrict__ A, const unsigned short* __restrict__ WT,
            const float* __restrict__ bias, float* __restrict__ Yf,
            unsigned short* __restrict__ Yb, const int* __restrict__ nperm,
            const int* __restrict__ meta) {
    __shared__ __align__(16) char smem[52224];
    unsigned short* Ab = (unsigned short*)smem;            // [64][136]
    unsigned short* Bs = (unsigned short*)(smem + 17408);  // [128][136]
    float* Cb = (float*)(smem + 17408);                    // alias Bs; stride 68
    const int WIDTH = NCB * 128;
    int row0 = blockIdx.x * 64;
    if (row0 >= meta[4]) return;
    int t = 0;
    while (t < 3 && row0 >= meta[t + 1]) t++;
    const unsigned short* WTt = WT + (size_t)t * WIDTH * K;
    int tid = threadIdx.x;
    int lane = tid & 63, w = tid >> 6;
    int m = lane & 15, q = lane >> 4;

#pragma unroll 1
    for (int cb = 0; cb < NCB; cb++) {
        f32x4 acc[4][2];
#pragma unroll
        for (int rt = 0; rt < 4; rt++)
#pragma unroll
            for (int ct = 0; ct < 2; ct++) acc[rt][ct] = (f32x4){0.f, 0.f, 0.f, 0.f};
#pragma unroll
        for (int kc = 0; kc < K / 128; kc++) {
            __syncthreads();
            {
#pragma unroll
                for (int it = 0; it < 8; it++) {
                    int idx = tid + it * 256;
                    int r = idx >> 5, c4 = (idx & 31) * 4;
                    int node = nperm[row0 + r];
                    float4 v = make_float4(0.f, 0.f, 0.f, 0.f);
                    if (node >= 0)
                        v = *(const float4*)(A + (size_t)node * K + kc * 128 + c4);
                    uint2 pk;
                    pk.x = f2bf(v.x) | (f2bf(v.y) << 16);
                    pk.y = f2bf(v.z) | (f2bf(v.w) << 16);
                    *(uint2*)(Ab + r * 136 + c4) = pk;
                }
            }
#pragma unroll
            for (int it = 0; it < 8; it++) {
                int idx = tid + it * 256;
                int n = idx >> 4, sg = idx & 15;
                *(uint4*)(Bs + n * 136 + sg * 8) =
                    *(const uint4*)(WTt + (size_t)(cb * 128 + n) * K + kc * 128 + sg * 8);
            }
            __syncthreads();
#pragma unroll
            for (int k0 = 0; k0 < 128; k0 += 32) {
                bf16x8 b0 = *(const bf16x8*)(Bs + (w * 32 + m) * 136 + k0 + q * 8);
                bf16x8 b1 = *(const bf16x8*)(Bs + (w * 32 + 16 + m) * 136 + k0 + q * 8);
#pragma unroll
                for (int rt = 0; rt < 4; rt++) {
                    bf16x8 a = *(const bf16x8*)(Ab + (rt * 16 + m) * 136 + k0 + q * 8);
                    acc[rt][0] = __builtin_amdgcn_mfma_f32_16x16x32_bf16(a, b0, acc[rt][0], 0, 0, 0);
                    acc[rt][1] = __builtin_amdgcn_mfma_f32_16x16x32_bf16(a, b1, acc[rt][1], 0, 0, 0);
                }
            }
        }
        // two 64-col halves through half-width Cb [64][68]
#pragma unroll 1
        for (int hf = 0; hf < 2; hf++) {
            __syncthreads();
            if ((w >> 1) == hf) {
#pragma unroll
                for (int rt = 0; rt < 4; rt++)
#pragma unroll
                    for (int ct = 0; ct < 2; ct++)
#pragma unroll
                        for (int r = 0; r < 4; r++)
                            Cb[(rt * 16 + q * 4 + r) * 68 + (w & 1) * 32 + ct * 16 + m] =
                                acc[rt][ct][r];
            }
            __syncthreads();
#pragma unroll
            for (int it = 0; it < 4; it++) {
                int idx = tid + it * 256;
                int row = idx >> 4, c4 = (idx & 15) * 4;
                float4 v = *(const float4*)(Cb + row * 68 + c4);
                float4 bv = *(const float4*)(bias + t * 128 + hf * 64 + c4);
                v.x += bv.x; v.y += bv.y; v.z += bv.z; v.w += bv.w;
                const float is2 = 0.70710678118654752f;
                v.x = 0.5f * v.x * (1.f + erff(v.x * is2));
                v.y = 0.5f * v.y * (1.f + erff(v.y * is2));
                v.z = 0.5f * v.z * (1.f + erff(v.z * is2));
                v.w = 0.5f * v.w * (1.f + erff(v.w * is2));
                int col = cb * 128 + hf * 64 + c4;
                *(float4*)(Yf + (size_t)(row0 + row) * WIDTH + col) = v;
                uint2 pk;
                pk.x = f2bf(v.x) | (f2bf(v.y) << 16);
                pk.y = f2bf(v.z) | (f2bf(v.w) << 16);
                *(uint2*)(Yb + (size_t)(row0 + row) * WIDTH + col) = pk;
            }
        }
    }
}

// ---------------- Wla GEMM, A resident in registers, row-space in/out ----------
// Fused skip-blend + LayerNorm (updates h fp32 and hb bf16), all rows.
template <int NCB>
__launch_bounds__(256) __global__
void k_gemm_reg(const unsigned short* __restrict__ A, const unsigned short* __restrict__ WT,
                const int* __restrict__ meta, const float* __restrict__ skipv,
                const float* __restrict__ gamma, const float* __restrict__ beta,
                float* __restrict__ hres, unsigned short* __restrict__ hbout) {
    __shared__ __align__(16) char smem[33792];
    unsigned short* Bs = (unsigned short*)smem;  // [128][128] linear, swizzled content
    float* Cbf = (float*)smem;                   // [64][132] f32 (alias)
    const int WIDTH = NCB * 128;
    int row0 = blockIdx.x * 64;
    if (row0 >= meta[4]) return;
    int t = 0;
    while (t < 3 && row0 >= meta[t + 1]) t++;
    const unsigned short* WTt = WT + (size_t)t * WIDTH * 128;
    int tid = threadIdx.x;
    int lane = tid & 63, w = tid >> 6;
    int m = lane & 15, q = lane >> 4;

    bf16x8 a[4][4];
#pragma unroll
    for (int rt = 0; rt < 4; rt++)
#pragma unroll
        for (int kk = 0; kk < 4; kk++)
            a[rt][kk] = *(const bf16x8*)(A + (size_t)(row0 + rt * 16 + m) * 128 + kk * 32 + q * 8);

#pragma unroll 1
    for (int cb = 0; cb < NCB; cb++) {
        f32x4 acc[4][2];
#pragma unroll
        for (int rt = 0; rt < 4; rt++)
#pragma unroll
            for (int ct = 0; ct < 2; ct++) acc[rt][ct] = (f32x4){0.f, 0.f, 0.f, 0.f};
        __syncthreads();
        {
            const unsigned short* pan = WTt + (size_t)cb * 128 * 128;
#pragma unroll
            for (int it = 0; it < 8; it++) {
                int chunk = (it << 2) | w;
                gload_lds16(pan + chunk * 512 + lane * 8, Bs + chunk * 512);
            }
        }
        __syncthreads();
#pragma unroll
        for (int kk = 0; kk < 4; kk++) {
            int c = (kk * 32 + q * 8) ^ ((m & 7) << 3);
            bf16x8 b0 = *(const bf16x8*)(Bs + (w * 32 + m) * 128 + c);
            bf16x8 b1 = *(const bf16x8*)(Bs + (w * 32 + 16 + m) * 128 + c);
#pragma unroll
            for (int rt = 0; rt < 4; rt++) {
                acc[rt][0] = __builtin_amdgcn_mfma_f32_16x16x32_bf16(a[rt][kk], b0, acc[rt][0], 0, 0, 0);
                acc[rt][1] = __builtin_amdgcn_mfma_f32_16x16x32_bf16(a[rt][kk], b1, acc[rt][1], 0, 0, 0);
            }
        }
        __syncthreads();
#pragma unroll
        for (int rt = 0; rt < 4; rt++)
#pragma unroll
            for (int ct = 0; ct < 2; ct++)
#pragma unroll
                for (int r = 0; r < 4; r++)
                    Cbf[(rt * 16 + q * 4 + r) * 132 + w * 32 + ct * 16 + m] = acc[rt][ct][r];
        __syncthreads();
        float alpha = 1.0f / (1.0f + __expf(-skipv[t]));
        int off = lane * 2;
        float2 g2 = *(const float2*)(gamma + off);
        float2 b2 = *(const float2*)(beta + off);
#pragma unroll 1
        for (int it = 0; it < 16; it++) {
            int row = w * 16 + it;
            float ax = Cbf[row * 132 + off];
            float ay = Cbf[row * 132 + off + 1];
            float2 h2 = *(const float2*)(hres + (size_t)(row0 + row) * 128 + off);
            float ox = ax * alpha + h2.x * (1.f - alpha);
            float oy = ay * alpha + h2.y * (1.f - alpha);
            float s = ox + oy;
#pragma unroll
            for (int mm = 1; mm < 64; mm <<= 1) s += __shfl_xor(s, mm);
            float mu = s * (1.0f / 128.0f);
            float dx = ox - mu, dy = oy - mu;
            float v2 = dx * dx + dy * dy;
#pragma unroll
            for (int mm = 1; mm < 64; mm <<= 1) v2 += __shfl_xor(v2, mm);
            float rs = rsqrtf(v2 * (1.0f / 128.0f) + 1e-5f);
            float vx = dx * rs * g2.x + b2.x;
            float vy = dy * rs * g2.y + b2.y;
            *(float2*)(hres + (size_t)(row0 + row) * 128 + off) = make_float2(vx, vy);
            *(unsigned*)(hbout + (size_t)(row0 + row) * 128 + off) = f2bf(vx) | (f2bf(vy) << 16);
        }
    }
}

// ---------------- kqv GEMM: row-space A, plane-major streaming output ----------
// Yb layout: [NCB][NROWS][128] — each phase's store is one dense 16KB burst.
template <int NCB, int SPLIT>
__launch_bounds__(256) __global__
void k_kqvP(const unsigned short* __restrict__ A, const unsigned short* __restrict__ WT,
            unsigned short* __restrict__ Yb, const int* __restrict__ meta) {
    __shared__ __align__(16) char smem[32768];
    unsigned short* Bs = (unsigned short*)smem;    // [128][128] swizzled content
    unsigned short* Cb16 = (unsigned short*)smem;  // [64][136] bf16 (alias)
    const int WIDTH = NCB * 128;
    int tile = blockIdx.x / SPLIT;
    int par = blockIdx.x % SPLIT;
    int row0 = tile * 64;
    if (row0 >= meta[4]) return;
    int t = 0;
    while (t < 3 && row0 >= meta[t + 1]) t++;
    const unsigned short* WTt = WT + (size_t)t * WIDTH * 128;
    int tid = threadIdx.x;
    int lane = tid & 63, w = tid >> 6;
    int m = lane & 15, q = lane >> 4;

    // A-frags: dense rows — each load instruction covers a 4KB block
    bf16x8 a[4][4];
#pragma unroll
    for (int rt = 0; rt < 4; rt++)
#pragma unroll
        for (int kk = 0; kk < 4; kk++)
            a[rt][kk] = *(const bf16x8*)(A + (size_t)(row0 + rt * 16 + m) * 128 + kk * 32 + q * 8);

#pragma unroll 1
    for (int cb = par; cb < NCB; cb += SPLIT) {
        f32x4 acc[4][2];
#pragma unroll
        for (int rt = 0; rt < 4; rt++)
#pragma unroll
            for (int ct = 0; ct < 2; ct++) acc[rt][ct] = (f32x4){0.f, 0.f, 0.f, 0.f};
        __syncthreads();  // prior epilogue's LDS reads done (Bs/Cb16 alias)
        {
            const unsigned short* pan = WTt + (size_t)cb * 128 * 128;
#pragma unroll
            for (int it = 0; it < 8; it++) {
                int chunk = (it << 2) | w;
                gload_lds16(pan + chunk * 512 + lane * 8, Bs + chunk * 512);
            }
        }
        __syncthreads();  // B staged
#pragma unroll
        for (int kk = 0; kk < 4; kk++) {
            int c = (kk * 32 + q * 8) ^ ((m & 7) << 3);
            bf16x8 b0 = *(const bf16x8*)(Bs + (w * 32 + m) * 128 + c);
            bf16x8 b1 = *(const bf16x8*)(Bs + (w * 32 + 16 + m) * 128 + c);
#pragma unroll
            for (int rt = 0; rt < 4; rt++) {
                acc[rt][0] = __builtin_amdgcn_mfma_f32_16x16x32_bf16(a[rt][kk], b0, acc[rt][0], 0, 0, 0);
                acc[rt][1] = __builtin_amdgcn_mfma_f32_16x16x32_bf16(a[rt][kk], b1, acc[rt][1], 0, 0, 0);
            }
        }
        __syncthreads();  // B reads done before Cb16 (alias) write
#pragma unroll
        for (int rt = 0; rt < 4; rt++)
#pragma unroll
            for (int ct = 0; ct < 2; ct++)
#pragma unroll
                for (int r = 0; r < 4; r++)
                    Cb16[(rt * 16 + q * 4 + r) * 136 + w * 32 + ct * 16 + m] =
                        (unsigned short)f2bf(acc[rt][ct][r]);
        __syncthreads();
        // dense 16KB burst: rows row0..row0+63 of plane cb
#pragma unroll
        for (int it = 0; it < 4; it++) {
            int idx = tid + it * 256;
            int row = idx >> 4, sg = idx & 15;
            *(uint4*)(Yb + ((size_t)cb * NROWS + row0 + row) * 128 + sg * 8) =
                *(const uint4*)(Cb16 + row * 136 + sg * 8);
        }
    }
}

// ---------------- fused edge pass over PERM rows, plane-major kqv ----------------
// kqv planes: 0 = k, 1..6 = qhat (cols (h*6+t -> (ht&3)*32) layout), 7..12 =
// vhat PER-TYPE: plane 7+t, cols h*32+d — same dense hoff pattern as k.
// qhat is dst-local: hoisted into 6 named registers per row; per-edge select
// via PURE NESTED-TERNARY EXPRESSION (no lambda — rule round 19).
#define QSEL(tt) ((tt) == 0 ? qh0 : ((tt) == 1 ? qh1 : ((tt) == 2 ? qh2 : \
                 ((tt) == 3 ? qh3 : ((tt) == 4 ? qh4 : qh5)))))
__global__ void k_edge(const unsigned short* __restrict__ kqv,
                       const int* __restrict__ offs, const unsigned* __restrict__ se,
                       unsigned short* __restrict__ aggb) {
    const size_t PL = (size_t)NROWS * 128;
    int lane = threadIdx.x & 63;
    int wid = blockIdx.x * (blockDim.x >> 6) + (threadIdx.x >> 6);
    int nw = gridDim.x * (blockDim.x >> 6);
    int h = lane >> 4;
    int i2 = (lane & 15) * 2;
    int hoff = h * 32 + i2;
    int h6 = h * 6;
    // per-lane qhat source offsets (ushort units, row term added later)
    size_t qo0 = (size_t)(1 + ((h6 + 0) >> 2)) * PL + (((h6 + 0) & 3) << 5) + i2;
    size_t qo1 = (size_t)(1 + ((h6 + 1) >> 2)) * PL + (((h6 + 1) & 3) << 5) + i2;
    size_t qo2 = (size_t)(1 + ((h6 + 2) >> 2)) * PL + (((h6 + 2) & 3) << 5) + i2;
    size_t qo3 = (size_t)(1 + ((h6 + 3) >> 2)) * PL + (((h6 + 3) & 3) << 5) + i2;
    size_t qo4 = (size_t)(1 + ((h6 + 4) >> 2)) * PL + (((h6 + 4) & 3) << 5) + i2;
    size_t qo5 = (size_t)(1 + ((h6 + 5) >> 2)) * PL + (((h6 + 5) & 3) << 5) + i2;
    for (int r = wid; r < NROWS; r += nw) {
        int e0 = offs[r], e1 = offs[r + 1];
        if (e0 >= e1) {
            *(unsigned*)(aggb + (size_t)r * 128 + hoff) = 0u;
            continue;
        }
        // hoist qhat[r] for all 6 types into named registers (dense row reads)
        size_t rb = (size_t)r * 128;
        unsigned qh0 = *(const unsigned*)(kqv + qo0 + rb);
        unsigned qh1 = *(const unsigned*)(kqv + qo1 + rb);
        unsigned qh2 = *(const unsigned*)(kqv + qo2 + rb);
        unsigned qh3 = *(const unsigned*)(kqv + qo3 + rb);
        unsigned qh4 = *(const unsigned*)(kqv + qo4 + rb);
        unsigned qh5 = *(const unsigned*)(kqv + qo5 + rb);
        float ax = 0.f, ay = 0.f, den = 0.f;
        int s[4], t[4];
#pragma unroll
        for (int u = 0; u < 4; u++) {
            s[u] = 0; t[u] = 0;
            if (e0 + u < e1) { unsigned p0 = se[e0 + u]; s[u] = p0 >> 3; t[u] = p0 & 7; }
        }
        int j = e0;
        while (j + 3 < e1) {
            unsigned ku[4], qu[4], vu[4];
#pragma unroll
            for (int u = 0; u < 4; u++) {
                ku[u] = *(const unsigned*)(kqv + (size_t)s[u] * 128 + hoff);
                vu[u] = *(const unsigned*)(kqv + (size_t)(7 + t[u]) * PL + (size_t)s[u] * 128 + hoff);
                qu[u] = QSEL(t[u]);
            }
            int jn = j + 4;
#pragma unroll
            for (int u = 0; u < 4; u++)
                if (jn + u < e1) { unsigned p0 = se[jn + u]; s[u] = p0 >> 3; t[u] = p0 & 7; }
            float p[4];
#pragma unroll
            for (int u = 0; u < 4; u++)
                p[u] = bf_lo(ku[u]) * bf_lo(qu[u]) + bf_hi(ku[u]) * bf_hi(qu[u]);
#pragma unroll
            for (int mm = 1; mm < 16; mm <<= 1) {
#pragma unroll
                for (int u = 0; u < 4; u++) p[u] += __shfl_xor(p[u], mm);
            }
#pragma unroll
            for (int u = 0; u < 4; u++) {
                float ex = __expf(p[u]);
                den += ex;
                ax += ex * bf_lo(vu[u]);
                ay += ex * bf_hi(vu[u]);
            }
            j = jn;
        }
        for (int u = 0; j < e1; j++, u++) {  // tail 0..3 edges
            unsigned ku = *(const unsigned*)(kqv + (size_t)s[u] * 128 + hoff);
            unsigned vu = *(const unsigned*)(kqv + (size_t)(7 + t[u]) * PL + (size_t)s[u] * 128 + hoff);
            unsigned qu = QSEL(t[u]);
            float p0 = bf_lo(ku) * bf_lo(qu) + bf_hi(ku) * bf_hi(qu);
            p0 += __shfl_xor(p0, 1);
            p0 += __shfl_xor(p0, 2);
            p0 += __shfl_xor(p0, 4);
            p0 += __shfl_xor(p0, 8);
            float ex = __expf(p0);
            den += ex;
            ax += ex * bf_lo(vu);
            ay += ex * bf_hi(vu);
        }
        float rr = (den > 0.f) ? (1.0f / den) : 0.f;
        unsigned pk = f2bf(ax * rr) | (f2bf(ay * rr) << 16);
        *(unsigned*)(aggb + (size_t)r * 128 + hoff) = pk;
    }
}
#undef QSEL

// ---------------- output projection (reads bf16 hb rows, scatters by nperm) ----
__global__ void k_out(const unsigned short* __restrict__ hb, const float* __restrict__ Wo,
                      const float* __restrict__ bo, float* __restrict__ out,
                      const int* __restrict__ nperm) {
    __shared__ float Ws[128 * 16];
    int tid = threadIdx.x;
#pragma unroll
    for (int it = 0; it < 2; it++) {
        int idx = (tid + it * 256) * 4;
        *(float4*)(&Ws[idx]) = *(const float4*)(Wo + idx);
    }
    __syncthreads();
    int nl = tid >> 4;
    int o = tid & 15;
    int row = blockIdx.x * 16 + nl;
    int node = nperm[row];
    float acc = bo[o];
    const unsigned short* hr = hb + (size_t)row * 128;
#pragma unroll
    for (int kk = 0; kk < 128; kk += 8) {
        uint4 hv = *(const uint4*)(hr + kk);
        acc += bf_lo(hv.x) * Ws[(kk + 0) * 16 + o] + bf_hi(hv.x) * Ws[(kk + 1) * 16 + o] +
               bf_lo(hv.y) * Ws[(kk + 2) * 16 + o] + bf_hi(hv.y) * Ws[(kk + 3) * 16 + o] +
               bf_lo(hv.z) * Ws[(kk + 4) * 16 + o] + bf_hi(hv.z) * Ws[(kk + 5) * 16 + o] +
               bf_lo(hv.w) * Ws[(kk + 6) * 16 + o] + bf_hi(hv.w) * Ws[(kk + 7) * 16 + o];
    }
    if (node >= 0) out[(size_t)node * 16 + o] = acc;
}

extern "C" void kernel_launch(void* const* d_in, const int* in_sizes, int n_in,
                              void* d_out, int out_size, void* d_ws, size_t ws_size,
                              hipStream_t stream) {
    const float* x       = (const float*)d_in[0];
    const float* adapt_W = (const float*)d_in[1];
    const float* adapt_b = (const float*)d_in[2];
    const float* Wk      = (const float*)d_in[3];
    const float* Wq      = (const float*)d_in[4];
    const float* Wv      = (const float*)d_in[5];
    const float* pri     = (const float*)d_in[6];
    const float* Wa      = (const float*)d_in[7];
    const float* Wm      = (const float*)d_in[8];
    const float* Wla     = (const float*)d_in[9];
    const float* skip    = (const float*)d_in[10];
    const float* gamma   = (const float*)d_in[11];
    const float* beta    = (const float*)d_in[12];
    const float* out_W   = (const float*)d_in[13];
    const float* out_b   = (const float*)d_in[14];
    const int* ntype     = (const int*)d_in[15];
    const int* etype     = (const int*)d_in[16];
    const int* src       = (const int*)d_in[17];
    const int* dst       = (const int*)d_in[18];
    float* out = (float*)d_out;

    char* p = (char*)d_ws;
    auto al = [](size_t v) { return (v + 255) & ~(size_t)255; };
    float* h  = (float*)p;          p += al((size_t)NROWS * 128 * 4);
    unsigned short* hb   = (unsigned short*)p; p += al((size_t)NROWS * 128 * 2);
    unsigned short* aggb = (unsigned short*)p; p += al((size_t)NROWS * 128 * 2);
    unsigned short* kqvb = (unsigned short*)p; p += al((size_t)NROWS * 1664 * 2);  // 13 planes
    unsigned short* adaptT = (unsigned short*)p; p += al((size_t)TNN * 128 * 256 * 2);
    unsigned short* WlaT   = (unsigned short*)p; p += al((size_t)LLL * TNN * 16384 * 2);
    unsigned short* Wf     = (unsigned short*)p; p += al((size_t)LLL * TNN * 1664 * 128 * 2);
    int* deg   = (int*)p; p += al((size_t)NROWS * 4);
    int* offs  = (int*)p; p += al((size_t)(NROWS + 1) * 4);
    int* cur   = (int*)p; p += al((size_t)NROWS * 4);
    unsigned* se = (unsigned*)p; p += al((size_t)EE * 4);
    int* nperm = (int*)p; p += al((size_t)NROWS * 4);
    int* iperm = (int*)p; p += al((size_t)NN * 4);
    int* bsum  = (int*)p; p += al(256 * 4);
    int* bpre  = (int*)p; p += al(256 * 4);
    int* ncnt  = (int*)p; p += al(64);
    int* ncur  = (int*)p; p += al(64);
    int* meta  = (int*)p; p += al(64);

    k_init<<<NB2, 256, 0, stream>>>(deg, cur, ncnt, ncur, nperm);
    k_count_types<<<(NN + 255) / 256, 256, 0, stream>>>(ntype, ncnt);
    k_meta<<<1, 64, 0, stream>>>(ncnt, meta);
    k_scatter_nodes<<<(NN + 255) / 256, 256, 0, stream>>>(ntype, meta, ncur, nperm, iperm);
    k_count_edges<<<(EE + 255) / 256, 256, 0, stream>>>(dst, iperm, deg);
    k_scan1<<<NB2, 256, 0, stream>>>(deg, bsum);
    k_scan2<<<1, 256, 0, stream>>>(bsum, bpre);
    k_scan3<<<NB2, 256, 0, stream>>>(deg, bpre, offs);
    k_scatter_edges<<<(EE + 255) / 256, 256, 0, stream>>>(dst, src, etype, iperm, offs, cur, se);

    k_wt<<<96, 256, 0, stream>>>(adapt_W, Wk, Wla, adaptT, Wf, WlaT);
    k_comb<<<384, 256, 0, stream>>>(Wq, Wa, Wv, Wm, pri, Wf);

    // adapt: h = gelu(x @ adaptT + b); x gathered by nperm, out in row space
    k_gemm<256, 1><<<TILES, 256, 0, stream>>>(
        x, adaptT, adapt_b, h, hb, nperm, meta);

    for (int l = 0; l < LLL; l++) {
        // fused K|Q|V: dense row-space A, plane-major streaming stores, 4-way split
        k_kqvP<13, 4><<<TILES * 4, 256, 0, stream>>>(
            hb, Wf + (size_t)l * TNN * 1664 * 128, kqvb, meta);

        k_edge<<<4096, 256, 0, stream>>>(kqvb, offs, se, aggb);

        // Wla GEMM + fused skip-blend + LayerNorm (row space)
        k_gemm_reg<1><<<TILES, 256, 0, stream>>>(
            aggb, WlaT + (size_t)l * TNN * 16384, meta,
            skip + (size_t)l * TNN, gamma + (size_t)l * HIDD, beta + (size_t)l * HIDD,
            h, hb);
    }

    k_out<<<NROWS / 16, 256, 0, stream>>>(hb, out_W, out_b, out, nperm);
}

// Round 10
// 562.028 us; speedup vs baseline: 1.0393x; 1.0393x over previous
//
#include <hip/hip_runtime.h>
#include <hip/hip_bf16.h>
#include <math.h>

#define NN    50000
#define EE    400000
#define NINP  256
#define HH    4
#define DD    32
#define HIDD  128
#define TNN   4
#define TEE   6
#define LLL   2
#define NOUTT 16
#define TILES 786                 // NN/64 + TNN + 1
#define NROWS 50304               // TILES*64, >= meta[4]
#define NB2   197                 // (NROWS+255)/256 scan blocks

// RULE: every LDS array row stride must be a multiple of 4 fp32 / 8 bf16
// elements so vector b128 accesses stay 16B-aligned (2 crashed rounds).
// RULE: every LDS staging loop must cover rows*cols/threads slots (round 6).
// RULE (round 10): don't feed MFMA straight from global — L2 latency stalls the
// pipe. (round 11): hold the k-invariant operand (A) in REGISTERS, B in LDS.
// RULE (round 12): Wf and WlaT are stored XOR-SWIZZLED (ushort col ^= (row&7)<<3
// per 128-col half-row) + panel-linear for linear global_load_lds staging.
// RULE (round 14): raw s_barrier + counted-vmcnt pipelining hung the GPU — do
// not reattempt. RULE (round 15): one-phase-per-block with SCATTERED A-gather
// regressed 45%. RULE (round 16): permuted row space (h/hb/aggb/kqvb by tile
// row, kqvb plane-major [13][NROWS][128]) made GEMM traffic dense — the win.
// RULE (round 19): NEVER use a reference-capturing lambda for register selects
// — AMDGPUPromoteAlloca turned the capture struct into 48KB of per-WG LDS with
// runtime indexing (2M bank conflicts, occupancy 63->24%, k_edge 66->134us).
// Use pure nested-ternary EXPRESSIONS over named registers instead.
// RULE (round 20): k_edge is gather-LINE-bound: vhat per-type contiguous
// ((t*4+h)*32+d) -> one dense 256B read per edge (FETCH 184->134MB, -9us).
// RULE (round 22): SPLIT=4 regressed (occupancy UNCHANGED at 23% — resident
// blocks are not grid-limited; extra blocks only add A re-fetch + prologues).
// k_kqvP is write-BW bound (~2.7TB/s, floor ~54us at bf16) — SPLIT stays 2.
// k_edge: 2048 blocks = 8192 waves = exactly one fully-resident generation.

typedef __attribute__((ext_vector_type(8))) short bf16x8;
typedef __attribute__((ext_vector_type(4))) float f32x4;

__device__ __forceinline__ float bf_lo(unsigned u) { return __uint_as_float(u << 16); }
__device__ __forceinline__ float bf_hi(unsigned u) { return __uint_as_float(u & 0xFFFF0000u); }
__device__ __forceinline__ unsigned f2bf(float f) {
    unsigned u = __float_as_uint(f);
    u += 0x7FFFu + ((u >> 16) & 1u);
    return (u >> 16);
}

// async global->LDS DMA, 16B per lane. LDS dest = wave-uniform base + lane*16.
__device__ __forceinline__ void gload_lds16(const unsigned short* g, unsigned short* l) {
    __builtin_amdgcn_global_load_lds(
        (__attribute__((address_space(1))) void*)(g),
        (__attribute__((address_space(3))) void*)(l), 16, 0, 0);
}

// ---------------- workspace init ----------------
__global__ void k_init(int* __restrict__ deg, int* __restrict__ cur, int* __restrict__ ncnt,
                       int* __restrict__ ncur, int* __restrict__ nperm) {
    int i = blockIdx.x * 256 + threadIdx.x;
    if (i < NROWS) { deg[i] = 0; cur[i] = 0; nperm[i] = -1; }
    if (i < 16) { ncnt[i] = 0; ncur[i] = 0; }
}

// ---------------- node typing / permutation ----------------
__global__ void k_count_types(const int* __restrict__ ntype, int* __restrict__ ncnt) {
    int n = blockIdx.x * 256 + threadIdx.x;
    int lane = threadIdx.x & 63;
    int t = (n < NN) ? ntype[n] : -1;
#pragma unroll
    for (int tt = 0; tt < TNN; tt++) {
        unsigned long long mask = __ballot(t == tt);
        if (mask && lane == (__ffsll((unsigned long long)mask) - 1))
            atomicAdd(&ncnt[tt], __popcll(mask));
    }
}
__global__ void k_meta(const int* __restrict__ ncnt, int* __restrict__ meta) {
    if (threadIdx.x == 0) {
        int acc = 0;
        meta[0] = 0;
        for (int t = 0; t < TNN; t++) { acc += ((ncnt[t] + 63) >> 6) << 6; meta[t + 1] = acc; }
    }
}
__global__ void k_scatter_nodes(const int* __restrict__ ntype, const int* __restrict__ meta,
                                int* __restrict__ ncur, int* __restrict__ nperm,
                                int* __restrict__ iperm) {
    int n = blockIdx.x * 256 + threadIdx.x;
    int lane = threadIdx.x & 63;
    int t = (n < NN) ? ntype[n] : -1;
#pragma unroll
    for (int tt = 0; tt < TNN; tt++) {
        unsigned long long mask = __ballot(t == tt);
        if (t == tt) {
            int rank = __popcll(mask & ((1ull << lane) - 1ull));
            int leader = __ffsll((unsigned long long)mask) - 1;
            int b = 0;
            if (rank == 0) b = atomicAdd(&ncur[tt], __popcll(mask));
            b = __shfl(b, leader);
            int slot = meta[tt] + b + rank;
            nperm[slot] = n;
            iperm[n] = slot;
        }
    }
}

// ---------------- CSR over PERMUTED rows ----------------
__global__ void k_count_edges(const int* __restrict__ dst, const int* __restrict__ iperm,
                              int* __restrict__ deg) {
    int e = blockIdx.x * 256 + threadIdx.x;
    if (e < EE) atomicAdd(&deg[iperm[dst[e]]], 1);
}
// 3-pass scan over NROWS
__global__ void k_scan1(const int* __restrict__ deg, int* __restrict__ bsum) {
    int i = blockIdx.x * 256 + threadIdx.x;
    int lane = threadIdx.x & 63, wv = threadIdx.x >> 6;
    __shared__ int ws[4];
    int x = (i < NROWS) ? deg[i] : 0;
#pragma unroll
    for (int off = 1; off < 64; off <<= 1) x += __shfl_xor(x, off);
    if (lane == 0) ws[wv] = x;
    __syncthreads();
    if (threadIdx.x == 0) bsum[blockIdx.x] = ws[0] + ws[1] + ws[2] + ws[3];
}
__global__ void k_scan2(const int* __restrict__ bsum, int* __restrict__ bpre) {
    __shared__ int ws[4];
    int tid = threadIdx.x, lane = tid & 63, wv = tid >> 6;
    int v = (tid < NB2) ? bsum[tid] : 0;
    int x = v;
#pragma unroll
    for (int off = 1; off < 64; off <<= 1) {
        int y = __shfl_up(x, off);
        if (lane >= off) x += y;
    }
    if (lane == 63) ws[wv] = x;
    __syncthreads();
    if (tid == 0) { int a = 0; for (int w = 0; w < 4; w++) { int s = ws[w]; ws[w] = a; a += s; } }
    __syncthreads();
    if (tid < NB2) bpre[tid] = x - v + ws[wv];
}
__global__ void k_scan3(const int* __restrict__ deg, const int* __restrict__ bpre,
                        int* __restrict__ offs) {
    int b = blockIdx.x;
    int tid = threadIdx.x, lane = tid & 63, wv = tid >> 6;
    int i = b * 256 + tid;
    __shared__ int ws[4];
    int v = (i < NROWS) ? deg[i] : 0;
    int x = v;
#pragma unroll
    for (int off = 1; off < 64; off <<= 1) {
        int y = __shfl_up(x, off);
        if (lane >= off) x += y;
    }
    if (lane == 63) ws[wv] = x;
    __syncthreads();
    if (tid == 0) { int a = 0; for (int w = 0; w < 4; w++) { int s = ws[w]; ws[w] = a; a += s; } }
    __syncthreads();
    if (i < NROWS) offs[i + 1] = x + ws[wv] + bpre[b];
    if (b == 0 && tid == 0) offs[0] = 0;
}
// writes packed (permuted_src<<3)|etype per CSR slot
__global__ void k_scatter_edges(const int* __restrict__ dst, const int* __restrict__ src,
                                const int* __restrict__ etype, const int* __restrict__ iperm,
                                const int* __restrict__ offs, int* __restrict__ cur,
                                unsigned* __restrict__ se) {
    int e = blockIdx.x * 256 + threadIdx.x;
    if (e < EE) {
        int d = iperm[dst[e]];
        int p = atomicAdd(&cur[d], 1);
        se[offs[d] + p] = ((unsigned)iperm[src[e]] << 3) | (unsigned)etype[e];
    }
}

// ---------------- weight transpose+convert: W[t][k][n] f32 -> WT[t][n][k] bf16 ----------
// adaptT: unswizzled (legacy k_gemm). Wf rows 0..127 and WlaT: XOR-swizzled
// (ushort col ^= (row&7)<<3) so DMA-staging GEMMs can read linearly.
__global__ void k_wt(const float* __restrict__ adapt_W, const float* __restrict__ Wk,
                     const float* __restrict__ Wla, unsigned short* __restrict__ adaptT,
                     unsigned short* __restrict__ Wf, unsigned short* __restrict__ WlaT) {
    __shared__ float Ts[64][68];  // 272B row stride
    int b = blockIdx.x, tid = threadIdx.x;
    const float* src;
    unsigned short* dst;
    int K, kt, nt, swz;
    if (b < 32) {
        int t = b >> 3, tile = b & 7;
        K = 256; kt = tile >> 1; nt = tile & 1; swz = 0;
        src = adapt_W + (size_t)t * 256 * 128;
        dst = adaptT + (size_t)t * 128 * 256;
    } else if (b < 64) {
        int b2 = b - 32, l = b2 >> 4, r = b2 & 15, t = r >> 2, tile = r & 3;
        K = 128; kt = tile >> 1; nt = tile & 1; swz = 1;
        src = Wk + (size_t)(l * 4 + t) * 16384;
        dst = Wf + (size_t)(l * TNN + t) * 1664 * 128;  // fused rows 0..127
    } else {
        int b2 = b - 64, l = b2 >> 4, r = b2 & 15, t = r >> 2, tile = r & 3;
        K = 128; kt = tile >> 1; nt = tile & 1; swz = 1;
        src = Wla + (size_t)(l * 4 + t) * 16384;
        dst = WlaT + (size_t)(l * 4 + t) * 16384;
    }
    int k0 = kt * 64, n0 = nt * 64;
#pragma unroll
    for (int it = 0; it < 4; it++) {  // 64x16 slots
        int idx = tid + it * 256;
        int row = idx >> 4, c4 = (idx & 15) * 4;
        *(float4*)(&Ts[row][c4]) = *(const float4*)(src + (size_t)(k0 + row) * 128 + n0 + c4);
    }
    __syncthreads();
#pragma unroll
    for (int it = 0; it < 2; it++) {  // 64x8 slots
        int idx = tid + it * 256;
        int nn = idx >> 3, sg = (idx & 7) * 8;
        uint4 pk;
        pk.x = f2bf(Ts[sg + 0][nn]) | (f2bf(Ts[sg + 1][nn]) << 16);
        pk.y = f2bf(Ts[sg + 2][nn]) | (f2bf(Ts[sg + 3][nn]) << 16);
        pk.z = f2bf(Ts[sg + 4][nn]) | (f2bf(Ts[sg + 5][nn]) << 16);
        pk.w = f2bf(Ts[sg + 6][nn]) | (f2bf(Ts[sg + 7][nn]) << 16);
        int col = k0 + sg;
        if (swz) col ^= (nn & 7) << 3;   // row = n0+nn, n0 % 8 == 0
        *(uint4*)(dst + (size_t)(n0 + nn) * K + col) = pk;
    }
}

// ---------------- combined weights into fused buffer (swizzled out) ----------------
// qhat columns: 128 + (h*6+t)*32 + o. vhat columns: 896 + (t*4+h)*32 + o
// (per-type contiguous so k_edge reads one dense 256B line per edge).
__global__ void k_comb(const float* __restrict__ Wq, const float* __restrict__ Wa,
                       const float* __restrict__ Wv, const float* __restrict__ Wm,
                       const float* __restrict__ pri, unsigned short* __restrict__ Wf) {
    __shared__ float Ls[128][36];
    __shared__ float Ss[32][36];
    __shared__ unsigned short Ot[32][136];
    int b = blockIdx.x, tid = threadIdx.x;
    int mode = b / 192;
    int rem = b % 192;
    int l = rem / 96;
    int rem2 = rem % 96;
    int t = rem2 / 24;
    int ht = rem2 % 24;
    int hh = ht / 6, te = ht % 6;
    const float* L = (mode == 0 ? Wq : Wv) + ((size_t)(l * TNN + t)) * 16384;
    const float* S = (mode == 0 ? Wa : Wm) + ((size_t)((l * HH + hh) * TEE + te)) * 1024;
    float ps = (mode == 0) ? pri[(l * HH + hh) * TEE + te] * 0.17677669529663687f : 1.0f;
#pragma unroll
    for (int it = 0; it < 4; it++) {  // 128x8 slots = 1024
        int idx = tid + it * 256;
        int kk = idx >> 3, c4 = (idx & 7) * 4;
        *(float4*)(&Ls[kk][c4]) = *(const float4*)(L + (size_t)kk * 128 + hh * 32 + c4);
    }
    {
        int r = tid >> 3, c4 = (tid & 7) * 4;
        *(float4*)(&Ss[r][c4]) = *(const float4*)(S + r * 32 + c4);
    }
    __syncthreads();
    int k = tid >> 1, half = tid & 1;
#pragma unroll
    for (int jj = 0; jj < 16; jj++) {
        int j = half * 16 + jj;
        float s = 0.f;
        if (mode == 0) {
#pragma unroll
            for (int o = 0; o < 32; o++) s += Ls[k][o] * Ss[j][o];
        } else {
#pragma unroll
            for (int d = 0; d < 32; d++) s += Ls[k][d] * Ss[d][j];
        }
        Ot[j][k] = (unsigned short)f2bf(s * ps);
    }
    __syncthreads();
    unsigned short* dst = Wf + ((size_t)(l * TNN + t) * 1664 + (mode == 0 ? 128 : 896)) * 128;
#pragma unroll
    for (int it = 0; it < 2; it++) {  // 32x16 slots
        int idx = tid + it * 256;
        int j = idx >> 4, sg = (idx & 15) * 8;
        uint4 pk = *(const uint4*)(&Ot[j][sg]);
        int jg = (mode == 0) ? (hh * 6 + te) * 32 + j : (te * 4 + hh) * 32 + j;
        *(uint4*)(dst + (size_t)jg * 128 + (sg ^ ((jg & 7) << 3))) = pk;
    }
}

// ---------------- adapt GEMM (K=256, fp32 A gathered by nperm; row-space out) ----
template <int K, int NCB>
__launch_bounds__(256) __global__
void k_gemm(const float* __restrict__ A, const unsigned short* __restrict__ WT,
            const float* __restrict__ bias, float* __restrict__ Yf,
            unsigned short* __restrict__ Yb, const int* __restrict__ nperm,
            const int* __restrict__ meta) {
    __shared__ __align__(16) char smem[52224];
    unsigned short* Ab = (unsigned short*)smem;            // [64][136]
    unsigned short* Bs = (unsigned short*)(smem + 17408);  // [128][136]
    float* Cb = (float*)(smem + 17408);                    // alias Bs; stride 68
    const int WIDTH = NCB * 128;
    int row0 = blockIdx.x * 64;
    if (row0 >= meta[4]) return;
    int t = 0;
    while (t < 3 && row0 >= meta[t + 1]) t++;
    const unsigned short* WTt = WT + (size_t)t * WIDTH * K;
    int tid = threadIdx.x;
    int lane = tid & 63, w = tid >> 6;
    int m = lane & 15, q = lane >> 4;

#pragma unroll 1
    for (int cb = 0; cb < NCB; cb++) {
        f32x4 acc[4][2];
#pragma unroll
        for (int rt = 0; rt < 4; rt++)
#pragma unroll
            for (int ct = 0; ct < 2; ct++) acc[rt][ct] = (f32x4){0.f, 0.f, 0.f, 0.f};
#pragma unroll
        for (int kc = 0; kc < K / 128; kc++) {
            __syncthreads();
            {
#pragma unroll
                for (int it = 0; it < 8; it++) {
                    int idx = tid + it * 256;
                    int r = idx >> 5, c4 = (idx & 31) * 4;
                    int node = nperm[row0 + r];
                    float4 v = make_float4(0.f, 0.f, 0.f, 0.f);
                    if (node >= 0)
                        v = *(const float4*)(A + (size_t)node * K + kc * 128 + c4);
                    uint2 pk;
                    pk.x = f2bf(v.x) | (f2bf(v.y) << 16);
                    pk.y = f2bf(v.z) | (f2bf(v.w) << 16);
                    *(uint2*)(Ab + r * 136 + c4) = pk;
                }
            }
#pragma unroll
            for (int it = 0; it < 8; it++) {
                int idx = tid + it * 256;
                int n = idx >> 4, sg = idx & 15;
                *(uint4*)(Bs + n * 136 + sg * 8) =
                    *(const uint4*)(WTt + (size_t)(cb * 128 + n) * K + kc * 128 + sg * 8);
            }
            __syncthreads();
#pragma unroll
            for (int k0 = 0; k0 < 128; k0 += 32) {
                bf16x8 b0 = *(const bf16x8*)(Bs + (w * 32 + m) * 136 + k0 + q * 8);
                bf16x8 b1 = *(const bf16x8*)(Bs + (w * 32 + 16 + m) * 136 + k0 + q * 8);
#pragma unroll
                for (int rt = 0; rt < 4; rt++) {
                    bf16x8 a = *(const bf16x8*)(Ab + (rt * 16 + m) * 136 + k0 + q * 8);
                    acc[rt][0] = __builtin_amdgcn_mfma_f32_16x16x32_bf16(a, b0, acc[rt][0], 0, 0, 0);
                    acc[rt][1] = __builtin_amdgcn_mfma_f32_16x16x32_bf16(a, b1, acc[rt][1], 0, 0, 0);
                }
            }
        }
        // two 64-col halves through half-width Cb [64][68]
#pragma unroll 1
        for (int hf = 0; hf < 2; hf++) {
            __syncthreads();
            if ((w >> 1) == hf) {
#pragma unroll
                for (int rt = 0; rt < 4; rt++)
#pragma unroll
                    for (int ct = 0; ct < 2; ct++)
#pragma unroll
                        for (int r = 0; r < 4; r++)
                            Cb[(rt * 16 + q * 4 + r) * 68 + (w & 1) * 32 + ct * 16 + m] =
                                acc[rt][ct][r];
            }
            __syncthreads();
#pragma unroll
            for (int it = 0; it < 4; it++) {
                int idx = tid + it * 256;
                int row = idx >> 4, c4 = (idx & 15) * 4;
                float4 v = *(const float4*)(Cb + row * 68 + c4);
                float4 bv = *(const float4*)(bias + t * 128 + hf * 64 + c4);
                v.x += bv.x; v.y += bv.y; v.z += bv.z; v.w += bv.w;
                const float is2 = 0.70710678118654752f;
                v.x = 0.5f * v.x * (1.f + erff(v.x * is2));
                v.y = 0.5f * v.y * (1.f + erff(v.y * is2));
                v.z = 0.5f * v.z * (1.f + erff(v.z * is2));
                v.w = 0.5f * v.w * (1.f + erff(v.w * is2));
                int col = cb * 128 + hf * 64 + c4;
                *(float4*)(Yf + (size_t)(row0 + row) * WIDTH + col) = v;
                uint2 pk;
                pk.x = f2bf(v.x) | (f2bf(v.y) << 16);
                pk.y = f2bf(v.z) | (f2bf(v.w) << 16);
                *(uint2*)(Yb + (size_t)(row0 + row) * WIDTH + col) = pk;
            }
        }
    }
}

// ---------------- Wla GEMM, A resident in registers, row-space in/out ----------
// Fused skip-blend + LayerNorm (updates h fp32 and hb bf16), all rows.
template <int NCB>
__launch_bounds__(256) __global__
void k_gemm_reg(const unsigned short* __restrict__ A, const unsigned short* __restrict__ WT,
                const int* __restrict__ meta, const float* __restrict__ skipv,
                const float* __restrict__ gamma, const float* __restrict__ beta,
                float* __restrict__ hres, unsigned short* __restrict__ hbout) {
    __shared__ __align__(16) char smem[33792];
    unsigned short* Bs = (unsigned short*)smem;  // [128][128] linear, swizzled content
    float* Cbf = (float*)smem;                   // [64][132] f32 (alias)
    const int WIDTH = NCB * 128;
    int row0 = blockIdx.x * 64;
    if (row0 >= meta[4]) return;
    int t = 0;
    while (t < 3 && row0 >= meta[t + 1]) t++;
    const unsigned short* WTt = WT + (size_t)t * WIDTH * 128;
    int tid = threadIdx.x;
    int lane = tid & 63, w = tid >> 6;
    int m = lane & 15, q = lane >> 4;

    bf16x8 a[4][4];
#pragma unroll
    for (int rt = 0; rt < 4; rt++)
#pragma unroll
        for (int kk = 0; kk < 4; kk++)
            a[rt][kk] = *(const bf16x8*)(A + (size_t)(row0 + rt * 16 + m) * 128 + kk * 32 + q * 8);

#pragma unroll 1
    for (int cb = 0; cb < NCB; cb++) {
        f32x4 acc[4][2];
#pragma unroll
        for (int rt = 0; rt < 4; rt++)
#pragma unroll
            for (int ct = 0; ct < 2; ct++) acc[rt][ct] = (f32x4){0.f, 0.f, 0.f, 0.f};
        __syncthreads();
        {
            const unsigned short* pan = WTt + (size_t)cb * 128 * 128;
#pragma unroll
            for (int it = 0; it < 8; it++) {
                int chunk = (it << 2) | w;
                gload_lds16(pan + chunk * 512 + lane * 8, Bs + chunk * 512);
            }
        }
        __syncthreads();
#pragma unroll
        for (int kk = 0; kk < 4; kk++) {
            int c = (kk * 32 + q * 8) ^ ((m & 7) << 3);
            bf16x8 b0 = *(const bf16x8*)(Bs + (w * 32 + m) * 128 + c);
            bf16x8 b1 = *(const bf16x8*)(Bs + (w * 32 + 16 + m) * 128 + c);
#pragma unroll
            for (int rt = 0; rt < 4; rt++) {
                acc[rt][0] = __builtin_amdgcn_mfma_f32_16x16x32_bf16(a[rt][kk], b0, acc[rt][0], 0, 0, 0);
                acc[rt][1] = __builtin_amdgcn_mfma_f32_16x16x32_bf16(a[rt][kk], b1, acc[rt][1], 0, 0, 0);
            }
        }
        __syncthreads();
#pragma unroll
        for (int rt = 0; rt < 4; rt++)
#pragma unroll
            for (int ct = 0; ct < 2; ct++)
#pragma unroll
                for (int r = 0; r < 4; r++)
                    Cbf[(rt * 16 + q * 4 + r) * 132 + w * 32 + ct * 16 + m] = acc[rt][ct][r];
        __syncthreads();
        float alpha = 1.0f / (1.0f + __expf(-skipv[t]));
        int off = lane * 2;
        float2 g2 = *(const float2*)(gamma + off);
        float2 b2 = *(const float2*)(beta + off);
#pragma unroll 1
        for (int it = 0; it < 16; it++) {
            int row = w * 16 + it;
            float ax = Cbf[row * 132 + off];
            float ay = Cbf[row * 132 + off + 1];
            float2 h2 = *(const float2*)(hres + (size_t)(row0 + row) * 128 + off);
            float ox = ax * alpha + h2.x * (1.f - alpha);
            float oy = ay * alpha + h2.y * (1.f - alpha);
            float s = ox + oy;
#pragma unroll
            for (int mm = 1; mm < 64; mm <<= 1) s += __shfl_xor(s, mm);
            float mu = s * (1.0f / 128.0f);
            float dx = ox - mu, dy = oy - mu;
            float v2 = dx * dx + dy * dy;
#pragma unroll
            for (int mm = 1; mm < 64; mm <<= 1) v2 += __shfl_xor(v2, mm);
            float rs = rsqrtf(v2 * (1.0f / 128.0f) + 1e-5f);
            float vx = dx * rs * g2.x + b2.x;
            float vy = dy * rs * g2.y + b2.y;
            *(float2*)(hres + (size_t)(row0 + row) * 128 + off) = make_float2(vx, vy);
            *(unsigned*)(hbout + (size_t)(row0 + row) * 128 + off) = f2bf(vx) | (f2bf(vy) << 16);
        }
    }
}

// ---------------- kqv GEMM: row-space A, plane-major streaming output ----------
// Yb layout: [NCB][NROWS][128] — each phase's store is one dense 16KB burst.
template <int NCB, int SPLIT>
__launch_bounds__(256) __global__
void k_kqvP(const unsigned short* __restrict__ A, const unsigned short* __restrict__ WT,
            unsigned short* __restrict__ Yb, const int* __restrict__ meta) {
    __shared__ __align__(16) char smem[32768];
    unsigned short* Bs = (unsigned short*)smem;    // [128][128] swizzled content
    unsigned short* Cb16 = (unsigned short*)smem;  // [64][136] bf16 (alias)
    const int WIDTH = NCB * 128;
    int tile = blockIdx.x / SPLIT;
    int par = blockIdx.x % SPLIT;
    int row0 = tile * 64;
    if (row0 >= meta[4]) return;
    int t = 0;
    while (t < 3 && row0 >= meta[t + 1]) t++;
    const unsigned short* WTt = WT + (size_t)t * WIDTH * 128;
    int tid = threadIdx.x;
    int lane = tid & 63, w = tid >> 6;
    int m = lane & 15, q = lane >> 4;

    // A-frags: dense rows — each load instruction covers a 4KB block
    bf16x8 a[4][4];
#pragma unroll
    for (int rt = 0; rt < 4; rt++)
#pragma unroll
        for (int kk = 0; kk < 4; kk++)
            a[rt][kk] = *(const bf16x8*)(A + (size_t)(row0 + rt * 16 + m) * 128 + kk * 32 + q * 8);

#pragma unroll 1
    for (int cb = par; cb < NCB; cb += SPLIT) {
        f32x4 acc[4][2];
#pragma unroll
        for (int rt = 0; rt < 4; rt++)
#pragma unroll
            for (int ct = 0; ct < 2; ct++) acc[rt][ct] = (f32x4){0.f, 0.f, 0.f, 0.f};
        __syncthreads();  // prior epilogue's LDS reads done (Bs/Cb16 alias)
        {
            const unsigned short* pan = WTt + (size_t)cb * 128 * 128;
#pragma unroll
            for (int it = 0; it < 8; it++) {
                int chunk = (it << 2) | w;
                gload_lds16(pan + chunk * 512 + lane * 8, Bs + chunk * 512);
            }
        }
        __syncthreads();  // B staged
#pragma unroll
        for (int kk = 0; kk < 4; kk++) {
            int c = (kk * 32 + q * 8) ^ ((m & 7) << 3);
            bf16x8 b0 = *(const bf16x8*)(Bs + (w * 32 + m) * 128 + c);
            bf16x8 b1 = *(const bf16x8*)(Bs + (w * 32 + 16 + m) * 128 + c);
#pragma unroll
            for (int rt = 0; rt < 4; rt++) {
                acc[rt][0] = __builtin_amdgcn_mfma_f32_16x16x32_bf16(a[rt][kk], b0, acc[rt][0], 0, 0, 0);
                acc[rt][1] = __builtin_amdgcn_mfma_f32_16x16x32_bf16(a[rt][kk], b1, acc[rt][1], 0, 0, 0);
            }
        }
        __syncthreads();  // B reads done before Cb16 (alias) write
#pragma unroll
        for (int rt = 0; rt < 4; rt++)
#pragma unroll
            for (int ct = 0; ct < 2; ct++)
#pragma unroll
                for (int r = 0; r < 4; r++)
                    Cb16[(rt * 16 + q * 4 + r) * 136 + w * 32 + ct * 16 + m] =
                        (unsigned short)f2bf(acc[rt][ct][r]);
        __syncthreads();
        // dense 16KB burst: rows row0..row0+63 of plane cb
#pragma unroll
        for (int it = 0; it < 4; it++) {
            int idx = tid + it * 256;
            int row = idx >> 4, sg = idx & 15;
            *(uint4*)(Yb + ((size_t)cb * NROWS + row0 + row) * 128 + sg * 8) =
                *(const uint4*)(Cb16 + row * 136 + sg * 8);
        }
    }
}

// ---------------- fused edge pass over PERM rows, plane-major kqv ----------------
// kqv planes: 0 = k, 1..6 = qhat (cols (h*6+t -> (ht&3)*32) layout), 7..12 =
// vhat PER-TYPE: plane 7+t, cols h*32+d — same dense hoff pattern as k.
// qhat is dst-local: hoisted into 6 named registers per row; per-edge select
// via PURE NESTED-TERNARY EXPRESSION (no lambda — rule round 19).
#define QSEL(tt) ((tt) == 0 ? qh0 : ((tt) == 1 ? qh1 : ((tt) == 2 ? qh2 : \
                 ((tt) == 3 ? qh3 : ((tt) == 4 ? qh4 : qh5)))))
__global__ void k_edge(const unsigned short* __restrict__ kqv,
                       const int* __restrict__ offs, const unsigned* __restrict__ se,
                       unsigned short* __restrict__ aggb) {
    const size_t PL = (size_t)NROWS * 128;
    int lane = threadIdx.x & 63;
    int wid = blockIdx.x * (blockDim.x >> 6) + (threadIdx.x >> 6);
    int nw = gridDim.x * (blockDim.x >> 6);
    int h = lane >> 4;
    int i2 = (lane & 15) * 2;
    int hoff = h * 32 + i2;
    int h6 = h * 6;
    // per-lane qhat source offsets (ushort units, row term added later)
    size_t qo0 = (size_t)(1 + ((h6 + 0) >> 2)) * PL + (((h6 + 0) & 3) << 5) + i2;
    size_t qo1 = (size_t)(1 + ((h6 + 1) >> 2)) * PL + (((h6 + 1) & 3) << 5) + i2;
    size_t qo2 = (size_t)(1 + ((h6 + 2) >> 2)) * PL + (((h6 + 2) & 3) << 5) + i2;
    size_t qo3 = (size_t)(1 + ((h6 + 3) >> 2)) * PL + (((h6 + 3) & 3) << 5) + i2;
    size_t qo4 = (size_t)(1 + ((h6 + 4) >> 2)) * PL + (((h6 + 4) & 3) << 5) + i2;
    size_t qo5 = (size_t)(1 + ((h6 + 5) >> 2)) * PL + (((h6 + 5) & 3) << 5) + i2;
    for (int r = wid; r < NROWS; r += nw) {
        int e0 = offs[r], e1 = offs[r + 1];
        if (e0 >= e1) {
            *(unsigned*)(aggb + (size_t)r * 128 + hoff) = 0u;
            continue;
        }
        // hoist qhat[r] for all 6 types into named registers (dense row reads)
        size_t rb = (size_t)r * 128;
        unsigned qh0 = *(const unsigned*)(kqv + qo0 + rb);
        unsigned qh1 = *(const unsigned*)(kqv + qo1 + rb);
        unsigned qh2 = *(const unsigned*)(kqv + qo2 + rb);
        unsigned qh3 = *(const unsigned*)(kqv + qo3 + rb);
        unsigned qh4 = *(const unsigned*)(kqv + qo4 + rb);
        unsigned qh5 = *(const unsigned*)(kqv + qo5 + rb);
        float ax = 0.f, ay = 0.f, den = 0.f;
        int s[4], t[4];
#pragma unroll
        for (int u = 0; u < 4; u++) {
            s[u] = 0; t[u] = 0;
            if (e0 + u < e1) { unsigned p0 = se[e0 + u]; s[u] = p0 >> 3; t[u] = p0 & 7; }
        }
        int j = e0;
        while (j + 3 < e1) {
            unsigned ku[4], qu[4], vu[4];
#pragma unroll
            for (int u = 0; u < 4; u++) {
                ku[u] = *(const unsigned*)(kqv + (size_t)s[u] * 128 + hoff);
                vu[u] = *(const unsigned*)(kqv + (size_t)(7 + t[u]) * PL + (size_t)s[u] * 128 + hoff);
                qu[u] = QSEL(t[u]);
            }
            int jn = j + 4;
#pragma unroll
            for (int u = 0; u < 4; u++)
                if (jn + u < e1) { unsigned p0 = se[jn + u]; s[u] = p0 >> 3; t[u] = p0 & 7; }
            float p[4];
#pragma unroll
            for (int u = 0; u < 4; u++)
                p[u] = bf_lo(ku[u]) * bf_lo(qu[u]) + bf_hi(ku[u]) * bf_hi(qu[u]);
#pragma unroll
            for (int mm = 1; mm < 16; mm <<= 1) {
#pragma unroll
                for (int u = 0; u < 4; u++) p[u] += __shfl_xor(p[u], mm);
            }
#pragma unroll
            for (int u = 0; u < 4; u++) {
                float ex = __expf(p[u]);
                den += ex;
                ax += ex * bf_lo(vu[u]);
                ay += ex * bf_hi(vu[u]);
            }
            j = jn;
        }
        for (int u = 0; j < e1; j++, u++) {  // tail 0..3 edges
            unsigned ku = *(const unsigned*)(kqv + (size_t)s[u] * 128 + hoff);
            unsigned vu = *(const unsigned*)(kqv + (size_t)(7 + t[u]) * PL + (size_t)s[u] * 128 + hoff);
            unsigned qu = QSEL(t[u]);
            float p0 = bf_lo(ku) * bf_lo(qu) + bf_hi(ku) * bf_hi(qu);
            p0 += __shfl_xor(p0, 1);
            p0 += __shfl_xor(p0, 2);
            p0 += __shfl_xor(p0, 4);
            p0 += __shfl_xor(p0, 8);
            float ex = __expf(p0);
            den += ex;
            ax += ex * bf_lo(vu);
            ay += ex * bf_hi(vu);
        }
        float rr = (den > 0.f) ? (1.0f / den) : 0.f;
        unsigned pk = f2bf(ax * rr) | (f2bf(ay * rr) << 16);
        *(unsigned*)(aggb + (size_t)r * 128 + hoff) = pk;
    }
}
#undef QSEL

// ---------------- output projection (reads bf16 hb rows, scatters by nperm) ----
__global__ void k_out(const unsigned short* __restrict__ hb, const float* __restrict__ Wo,
                      const float* __restrict__ bo, float* __restrict__ out,
                      const int* __restrict__ nperm) {
    __shared__ float Ws[128 * 16];
    int tid = threadIdx.x;
#pragma unroll
    for (int it = 0; it < 2; it++) {
        int idx = (tid + it * 256) * 4;
        *(float4*)(&Ws[idx]) = *(const float4*)(Wo + idx);
    }
    __syncthreads();
    int nl = tid >> 4;
    int o = tid & 15;
    int row = blockIdx.x * 16 + nl;
    int node = nperm[row];
    float acc = bo[o];
    const unsigned short* hr = hb + (size_t)row * 128;
#pragma unroll
    for (int kk = 0; kk < 128; kk += 8) {
        uint4 hv = *(const uint4*)(hr + kk);
        acc += bf_lo(hv.x) * Ws[(kk + 0) * 16 + o] + bf_hi(hv.x) * Ws[(kk + 1) * 16 + o] +
               bf_lo(hv.y) * Ws[(kk + 2) * 16 + o] + bf_hi(hv.y) * Ws[(kk + 3) * 16 + o] +
               bf_lo(hv.z) * Ws[(kk + 4) * 16 + o] + bf_hi(hv.z) * Ws[(kk + 5) * 16 + o] +
               bf_lo(hv.w) * Ws[(kk + 6) * 16 + o] + bf_hi(hv.w) * Ws[(kk + 7) * 16 + o];
    }
    if (node >= 0) out[(size_t)node * 16 + o] = acc;
}

extern "C" void kernel_launch(void* const* d_in, const int* in_sizes, int n_in,
                              void* d_out, int out_size, void* d_ws, size_t ws_size,
                              hipStream_t stream) {
    const float* x       = (const float*)d_in[0];
    const float* adapt_W = (const float*)d_in[1];
    const float* adapt_b = (const float*)d_in[2];
    const float* Wk      = (const float*)d_in[3];
    const float* Wq      = (const float*)d_in[4];
    const float* Wv      = (const float*)d_in[5];
    const float* pri     = (const float*)d_in[6];
    const float* Wa      = (const float*)d_in[7];
    const float* Wm      = (const float*)d_in[8];
    const float* Wla     = (const float*)d_in[9];
    const float* skip    = (const float*)d_in[10];
    const float* gamma   = (const float*)d_in[11];
    const float* beta    = (const float*)d_in[12];
    const float* out_W   = (const float*)d_in[13];
    const float* out_b   = (const float*)d_in[14];
    const int* ntype     = (const int*)d_in[15];
    const int* etype     = (const int*)d_in[16];
    const int* src       = (const int*)d_in[17];
    const int* dst       = (const int*)d_in[18];
    float* out = (float*)d_out;

    char* p = (char*)d_ws;
    auto al = [](size_t v) { return (v + 255) & ~(size_t)255; };
    float* h  = (float*)p;          p += al((size_t)NROWS * 128 * 4);
    unsigned short* hb   = (unsigned short*)p; p += al((size_t)NROWS * 128 * 2);
    unsigned short* aggb = (unsigned short*)p; p += al((size_t)NROWS * 128 * 2);
    unsigned short* kqvb = (unsigned short*)p; p += al((size_t)NROWS * 1664 * 2);  // 13 planes
    unsigned short* adaptT = (unsigned short*)p; p += al((size_t)TNN * 128 * 256 * 2);
    unsigned short* WlaT   = (unsigned short*)p; p += al((size_t)LLL * TNN * 16384 * 2);
    unsigned short* Wf     = (unsigned short*)p; p += al((size_t)LLL * TNN * 1664 * 128 * 2);
    int* deg   = (int*)p; p += al((size_t)NROWS * 4);
    int* offs  = (int*)p; p += al((size_t)(NROWS + 1) * 4);
    int* cur   = (int*)p; p += al((size_t)NROWS * 4);
    unsigned* se = (unsigned*)p; p += al((size_t)EE * 4);
    int* nperm = (int*)p; p += al((size_t)NROWS * 4);
    int* iperm = (int*)p; p += al((size_t)NN * 4);
    int* bsum  = (int*)p; p += al(256 * 4);
    int* bpre  = (int*)p; p += al(256 * 4);
    int* ncnt  = (int*)p; p += al(64);
    int* ncur  = (int*)p; p += al(64);
    int* meta  = (int*)p; p += al(64);

    k_init<<<NB2, 256, 0, stream>>>(deg, cur, ncnt, ncur, nperm);
    k_count_types<<<(NN + 255) / 256, 256, 0, stream>>>(ntype, ncnt);
    k_meta<<<1, 64, 0, stream>>>(ncnt, meta);
    k_scatter_nodes<<<(NN + 255) / 256, 256, 0, stream>>>(ntype, meta, ncur, nperm, iperm);
    k_count_edges<<<(EE + 255) / 256, 256, 0, stream>>>(dst, iperm, deg);
    k_scan1<<<NB2, 256, 0, stream>>>(deg, bsum);
    k_scan2<<<1, 256, 0, stream>>>(bsum, bpre);
    k_scan3<<<NB2, 256, 0, stream>>>(deg, bpre, offs);
    k_scatter_edges<<<(EE + 255) / 256, 256, 0, stream>>>(dst, src, etype, iperm, offs, cur, se);

    k_wt<<<96, 256, 0, stream>>>(adapt_W, Wk, Wla, adaptT, Wf, WlaT);
    k_comb<<<384, 256, 0, stream>>>(Wq, Wa, Wv, Wm, pri, Wf);

    // adapt: h = gelu(x @ adaptT + b); x gathered by nperm, out in row space
    k_gemm<256, 1><<<TILES, 256, 0, stream>>>(
        x, adaptT, adapt_b, h, hb, nperm, meta);

    for (int l = 0; l < LLL; l++) {
        // fused K|Q|V: dense row-space A, plane-major streaming stores
        k_kqvP<13, 2><<<TILES * 2, 256, 0, stream>>>(
            hb, Wf + (size_t)l * TNN * 1664 * 128, kqvb, meta);

        // exactly one resident wave generation: 2048 blocks x 4 waves = 8192
        k_edge<<<2048, 256, 0, stream>>>(kqvb, offs, se, aggb);

        // Wla GEMM + fused skip-blend + LayerNorm (row space)
        k_gemm_reg<1><<<TILES, 256, 0, stream>>>(
            aggb, WlaT + (size_t)l * TNN * 16384, meta,
            skip + (size_t)l * TNN, gamma + (size_t)l * HIDD, beta + (size_t)l * HIDD,
            h, hb);
    }

    k_out<<<NROWS / 16, 256, 0, stream>>>(hb, out_W, out_b, out, nperm);
}